// Round 1
// baseline (1279.024 us; speedup 1.0000x reference)
//
#include <hip/hip_runtime.h>

// ---------------------------------------------------------------------------
// SpatialAttention, N=8192, D=H=512, GAMMA=0.5
//   sr = (x Wq_r)(x Wk_r)^T * 1/sqrt(H), masked(real)-> -1e9 (=> exp 0)
//   sf = same with fake weights/mask
//   S  = exp(sr) + 0.5*exp(sf)          (the /1.5 cancels in attn & cntx)
//   attn = S / rowsum(S);  cntx = attn @ (x Wv + bv)
// Outputs: d_out = [cntx (N*D f32) | attn (N*N f32)]
//
// Numerics: fp16 operands + fp32-accum MFMA => score err ~7e-4 std, threshold
// is max*2^-8 (~4e-3 relative) -> ~5.6 sigma margin.
// ---------------------------------------------------------------------------

#define K_N 8192
#define K_D 512

typedef float  f32x4 __attribute__((ext_vector_type(4)));
typedef _Float16 f16x8 __attribute__((ext_vector_type(8)));
typedef unsigned short u16;

__device__ __forceinline__ u16 f2h(float f) {
  _Float16 h = (_Float16)f;
  return __builtin_bit_cast(u16, h);
}

// ---------------------------------------------------------------------------
// Mask dtype detector: bool masks may arrive as 1-byte (np.bool_) or 4-byte
// (int32/float). For 4-byte 0/1 values, bytes at offset %4==1 are always 0;
// for 1-byte masks ~half are nonzero. flag=1 -> byte masks, 0 -> 4-byte.
// ---------------------------------------------------------------------------
__global__ void k_detect(const unsigned char* __restrict__ m, int* __restrict__ flag) {
  __shared__ int any;
  if (threadIdx.x == 0) any = 0;
  __syncthreads();
  int local = 0;
  for (int i = threadIdx.x; i < 65536; i += 256)
    local |= m[4 * i + 1];
  if (local) atomicOr(&any, 1);
  __syncthreads();
  if (threadIdx.x == 0) *flag = any ? 1 : 0;
}

__device__ __forceinline__ bool mask_at(const void* mask, int mode, size_t idx) {
  if (mode) return ((const unsigned char*)mask)[idx] != 0;
  return ((const int*)mask)[idx] != 0;
}

// ---------------------------------------------------------------------------
// x (f32) -> fp16
// ---------------------------------------------------------------------------
__global__ void k_cvt_x(const float* __restrict__ x, u16* __restrict__ xh) {
  int i = blockIdx.x * 256 + threadIdx.x;           // float4 index, 1M total
  float4 v = ((const float4*)x)[i];
  ushort4 o;
  o.x = f2h(v.x); o.y = f2h(v.y); o.z = f2h(v.z); o.w = f2h(v.w);
  ((ushort4*)xh)[i] = o;
}

// ---------------------------------------------------------------------------
// Tiled transpose (64x64 tiles): out[c][r] = in[r][c]; optional f32->fp16.
// ---------------------------------------------------------------------------
template <int IN_F32>
__global__ void k_transpose(const void* __restrict__ in, u16* __restrict__ out,
                            int R, int C) {
  __shared__ u16 sm[64][65];
  int c0 = blockIdx.x * 64, r0 = blockIdx.y * 64;
#pragma unroll
  for (int e = 0; e < 16; e++) {
    int idx = e * 256 + threadIdx.x;
    int i = idx >> 6, j = idx & 63;
    u16 h;
    if (IN_F32) h = f2h(((const float*)in)[(size_t)(r0 + i) * C + c0 + j]);
    else        h = ((const u16*)in)[(size_t)(r0 + i) * C + c0 + j];
    sm[i][j] = h;
  }
  __syncthreads();
#pragma unroll
  for (int e = 0; e < 16; e++) {
    int idx = e * 256 + threadIdx.x;
    int j = idx >> 6, i = idx & 63;
    out[(size_t)(c0 + j) * R + r0 + i] = sm[i][j];
  }
}

// ---------------------------------------------------------------------------
// Core fp16 MFMA GEMM tile: C(128x128) += A(128xK) * Bt(128xK)^T
//   A row-major [M][lda] (fp16 bits, or fp32 if A_F32 -> converted in-flight)
//   Bt row-major [Ncols][ldb] = B^T (fp16 bits)
// 256 threads = 4 waves in 2x2 grid, each wave 64x64 via 4x4 x 16x16x32 MFMA.
// LDS tiles [128][64] fp16 with chunk swizzle pk = k16 ^ (row&7) so that
// ds_read_b128 fragment reads are bank-conflict-free.
// ---------------------------------------------------------------------------
template <int A_F32>
__device__ __forceinline__ void gemm_core(const void* __restrict__ Ap, int lda,
                                          const u16* __restrict__ Bt, int ldb,
                                          int rowBase, int colBase, int K,
                                          u16* sA, u16* sB, f32x4 (&acc)[4][4]) {
  const int tid   = threadIdx.x;
  const int lane  = tid & 63;
  const int waveM = tid >> 7;           // 0..1
  const int waveN = (tid >> 6) & 1;     // 0..1
  const int lrow  = lane & 15;
  const int lk    = lane >> 4;          // 0..3

  for (int k0 = 0; k0 < K; k0 += 64) {
    __syncthreads();   // previous compute done before LDS overwrite
#pragma unroll
    for (int g = 0; g < 4; g++) {
      int cid = g * 256 + tid;          // 16B chunk id, 0..1023
      int row = cid >> 3;
      int pk  = cid & 7;
      int k16 = pk ^ (row & 7);         // logical k-chunk stored at physical pk
      if (A_F32) {
        const float* s = (const float*)Ap + (size_t)(rowBase + row) * lda + k0 + k16 * 8;
        float4 v0 = *(const float4*)s;
        float4 v1 = *(const float4*)(s + 4);
        ushort4 h0, h1;
        h0.x = f2h(v0.x); h0.y = f2h(v0.y); h0.z = f2h(v0.z); h0.w = f2h(v0.w);
        h1.x = f2h(v1.x); h1.y = f2h(v1.y); h1.z = f2h(v1.z); h1.w = f2h(v1.w);
        *(ushort4*)&sA[cid * 8]     = h0;
        *(ushort4*)&sA[cid * 8 + 4] = h1;
      } else {
        uint4 v = *(const uint4*)((const u16*)Ap + (size_t)(rowBase + row) * lda + k0 + k16 * 8);
        *(uint4*)&sA[cid * 8] = v;
      }
      uint4 w = *(const uint4*)(Bt + (size_t)(colBase + row) * ldb + k0 + k16 * 8);
      *(uint4*)&sB[cid * 8] = w;
    }
    __syncthreads();   // staging visible
#pragma unroll
    for (int kk = 0; kk < 2; kk++) {
      f16x8 af[4], bfv[4];
      int k16 = kk * 4 + lk;
#pragma unroll
      for (int mb = 0; mb < 4; mb++) {
        int r = waveM * 64 + mb * 16 + lrow;
        af[mb] = *(const f16x8*)&sA[r * 64 + ((k16 ^ (r & 7)) << 3)];
      }
#pragma unroll
      for (int nb = 0; nb < 4; nb++) {
        int c = waveN * 64 + nb * 16 + lrow;
        bfv[nb] = *(const f16x8*)&sB[c * 64 + ((k16 ^ (c & 7)) << 3)];
      }
#pragma unroll
      for (int mb = 0; mb < 4; mb++)
#pragma unroll
        for (int nb = 0; nb < 4; nb++)
          acc[mb][nb] = __builtin_amdgcn_mfma_f32_16x16x32_f16(af[mb], bfv[nb], acc[mb][nb], 0, 0, 0);
    }
  }
}

// ---------------------------------------------------------------------------
// Projections: z=0..3 -> Q_r,K_r,Q_f,K_f (fp16), z=4 -> V=x@Wv+bv (fp16)
// ---------------------------------------------------------------------------
__global__ __launch_bounds__(256) void k_proj(const u16* __restrict__ xh,
                                              const u16* __restrict__ wt,
                                              u16* __restrict__ qr, u16* __restrict__ kr,
                                              u16* __restrict__ qf, u16* __restrict__ kf,
                                              u16* __restrict__ vh,
                                              const float* __restrict__ bv) {
  __shared__ u16 sA[128 * 64], sB[128 * 64];
  f32x4 acc[4][4] = {};
  const int z = blockIdx.z;
  const int rowBase = blockIdx.y * 128, colBase = blockIdx.x * 128;
  gemm_core<0>(xh, K_D, wt + (size_t)z * 262144, K_D, rowBase, colBase, K_D, sA, sB, acc);

  u16* out = (z == 0) ? qr : (z == 1) ? kr : (z == 2) ? qf : (z == 3) ? kf : vh;
  const int lane = threadIdx.x & 63;
  const int waveM = threadIdx.x >> 7, waveN = (threadIdx.x >> 6) & 1;
  const int lrow = lane & 15, lk = lane >> 4;
#pragma unroll
  for (int mb = 0; mb < 4; mb++)
#pragma unroll
    for (int nb = 0; nb < 4; nb++)
#pragma unroll
      for (int r = 0; r < 4; r++) {
        int grow = rowBase + waveM * 64 + mb * 16 + lk * 4 + r;
        int gcol = colBase + waveN * 64 + nb * 16 + lrow;
        float v = acc[mb][nb][r];
        if (z == 4) v += bv[gcol];
        out[(size_t)grow * K_D + gcol] = f2h(v);
      }
}

// ---------------------------------------------------------------------------
// Scores: S-tile = Q @ K^T * scale -> masked exp.
//   FAKE=0: attn = exp_r      FAKE=1: attn += 0.5*exp_f, emit row partials
// ---------------------------------------------------------------------------
template <int FAKE>
__global__ __launch_bounds__(256) void k_scores(const u16* __restrict__ Q,
                                                const u16* __restrict__ Kt,
                                                const void* __restrict__ mask,
                                                const int* __restrict__ flag,
                                                float* __restrict__ attn,
                                                float* __restrict__ partial) {
  __shared__ u16 sA[128 * 64], sB[128 * 64];
  f32x4 acc[4][4] = {};
  const int rowBase = blockIdx.y * 128, colBase = blockIdx.x * 128;
  gemm_core<0>(Q, K_D, Kt, K_D, rowBase, colBase, K_D, sA, sB, acc);

  const float scale = 0.04419417382415922f;   // 1/sqrt(512)
  const int mode = *flag;
  const int lane = threadIdx.x & 63;
  const int waveM = threadIdx.x >> 7, waveN = (threadIdx.x >> 6) & 1;
  const int lrow = lane & 15, lk = lane >> 4;
#pragma unroll
  for (int mb = 0; mb < 4; mb++)
#pragma unroll
    for (int r = 0; r < 4; r++) {
      int grow = rowBase + waveM * 64 + mb * 16 + lk * 4 + r;
      float rs = 0.f;
#pragma unroll
      for (int nb = 0; nb < 4; nb++) {
        int gcol = colBase + waveN * 64 + nb * 16 + lrow;
        size_t oi = (size_t)grow * K_N + gcol;
        bool msk = mask_at(mask, mode, oi);
        float e = msk ? 0.f : __expf(acc[mb][nb][r] * scale);
        if (FAKE) {
          float v = attn[oi] + 0.5f * e;
          attn[oi] = v;
          rs += v;
        } else {
          attn[oi] = e;
        }
      }
      if (FAKE) {
        rs += __shfl_xor(rs, 1, 64);
        rs += __shfl_xor(rs, 2, 64);
        rs += __shfl_xor(rs, 4, 64);
        rs += __shfl_xor(rs, 8, 64);
        if (lrow == 0)
          partial[(size_t)grow * 128 + blockIdx.x * 2 + waveN] = rs;
      }
    }
}

// ---------------------------------------------------------------------------
// Row-sum reduce: 128 partials per row -> 1/rowsum
// ---------------------------------------------------------------------------
__global__ void k_rowsum(const float* __restrict__ partial, float* __restrict__ inv) {
  int r = blockIdx.x * 256 + threadIdx.x;
  const float* p = partial + (size_t)r * 128;
  float s = 0.f;
#pragma unroll 8
  for (int j = 0; j < 128; j++) s += p[j];
  inv[r] = 1.0f / s;
}

// ---------------------------------------------------------------------------
// Normalize attn in place
// ---------------------------------------------------------------------------
__global__ void k_norm(float* __restrict__ attn, const float* __restrict__ inv) {
  const size_t total = (size_t)K_N * K_N / 4;
  for (size_t i = (size_t)blockIdx.x * 256 + threadIdx.x; i < total;
       i += (size_t)gridDim.x * 256) {
    int row = (int)(i >> 11);                 // 2048 float4 per row
    float s = inv[row];
    float4 v = ((float4*)attn)[i];
    v.x *= s; v.y *= s; v.z *= s; v.w *= s;
    ((float4*)attn)[i] = v;
  }
}

// ---------------------------------------------------------------------------
// cntx = attn(normalized, f32 -> fp16 in staging) @ V   (Bt = V^T fp16)
// ---------------------------------------------------------------------------
__global__ __launch_bounds__(256) void k_cntx(const float* __restrict__ attn,
                                              const u16* __restrict__ vt,
                                              float* __restrict__ out) {
  __shared__ u16 sA[128 * 64], sB[128 * 64];
  f32x4 acc[4][4] = {};
  const int rowBase = blockIdx.y * 128, colBase = blockIdx.x * 128;
  gemm_core<1>(attn, K_N, vt, K_N, rowBase, colBase, K_N, sA, sB, acc);

  const int lane = threadIdx.x & 63;
  const int waveM = threadIdx.x >> 7, waveN = (threadIdx.x >> 6) & 1;
  const int lrow = lane & 15, lk = lane >> 4;
#pragma unroll
  for (int mb = 0; mb < 4; mb++)
#pragma unroll
    for (int nb = 0; nb < 4; nb++)
#pragma unroll
      for (int r = 0; r < 4; r++) {
        int grow = rowBase + waveM * 64 + mb * 16 + lk * 4 + r;
        int gcol = colBase + waveN * 64 + nb * 16 + lrow;
        out[(size_t)grow * K_D + gcol] = acc[mb][nb][r];
      }
}

// ---------------------------------------------------------------------------
extern "C" void kernel_launch(void* const* d_in, const int* in_sizes, int n_in,
                              void* d_out, int out_size, void* d_ws, size_t ws_size,
                              hipStream_t stream) {
  const float* x   = (const float*)d_in[0];
  const void*  mR  = d_in[1];
  const void*  mF  = d_in[2];
  const float* WqR = (const float*)d_in[3];
  const float* WkR = (const float*)d_in[4];
  const float* WqF = (const float*)d_in[5];
  const float* WkF = (const float*)d_in[6];
  const float* Wv  = (const float*)d_in[7];
  const float* bv  = (const float*)d_in[8];

  // workspace: 7 fp16 [N][D]-sized tensors + 5 transposed weights (~59 MB)
  const size_t ND = (size_t)K_N * K_D;
  u16* xh = (u16*)d_ws;
  u16* qr = xh + ND;
  u16* kr = qr + ND;
  u16* qf = kr + ND;
  u16* kf = qf + ND;
  u16* vh = kf + ND;
  u16* vt = vh + ND;
  u16* wt = vt + ND;              // 5 * 512*512

  float* cntx = (float*)d_out;
  float* attn = cntx + ND;
  // scratch parked inside the cntx region (overwritten last by k_cntx):
  float* partial = cntx;                          // [8192][128]
  float* inv     = cntx + (size_t)K_N * 128;      // [8192]
  int*   flag    = (int*)(cntx + (size_t)K_N * 128 + K_N);

  k_detect<<<1, 256, 0, stream>>>((const unsigned char*)mR, flag);
  k_cvt_x<<<4096, 256, 0, stream>>>(x, xh);

  k_transpose<1><<<dim3(8, 8), 256, 0, stream>>>(WqR, wt + 0 * 262144, 512, 512);
  k_transpose<1><<<dim3(8, 8), 256, 0, stream>>>(WkR, wt + 1 * 262144, 512, 512);
  k_transpose<1><<<dim3(8, 8), 256, 0, stream>>>(WqF, wt + 2 * 262144, 512, 512);
  k_transpose<1><<<dim3(8, 8), 256, 0, stream>>>(WkF, wt + 3 * 262144, 512, 512);
  k_transpose<1><<<dim3(8, 8), 256, 0, stream>>>(Wv,  wt + 4 * 262144, 512, 512);

  k_proj<<<dim3(4, 64, 5), 256, 0, stream>>>(xh, wt, qr, kr, qf, kf, vh, bv);
  k_transpose<0><<<dim3(8, 128), 256, 0, stream>>>(vh, vt, K_N, K_D);

  k_scores<0><<<dim3(64, 64), 256, 0, stream>>>(qr, kr, mR, flag, attn, nullptr);
  k_scores<1><<<dim3(64, 64), 256, 0, stream>>>(qf, kf, mF, flag, attn, partial);

  k_rowsum<<<32, 256, 0, stream>>>(partial, inv);
  k_norm<<<8192, 256, 0, stream>>>(attn, inv);
  k_cntx<<<dim3(4, 64), 256, 0, stream>>>(attn, vt, cntx);
}